// Round 6
// baseline (322.010 us; speedup 1.0000x reference)
//
#include <hip/hip_runtime.h>
#include <hip/hip_bf16.h>

static constexpr int N = 2048;
static constexpr int D = 128;
static constexpr int F = 8;
static constexpr int RS = 256;   // packed row stride (ushorts): [hi(128) | lo(128)]

// ---------------- workspace layout (bytes) ----------------
static constexpr size_t OFF_LOSS = 0;        // float
static constexpr size_t OFF_CNT  = 4;        // int
static constexpr size_t OFF_PSIM = 1024;                      // u64 [16][F*N] partial sim keys
static constexpr size_t OFF_PLAB = 1024 + 2097152;            // u64 [16][F*N]
static constexpr size_t OFF_RNQ  = OFF_PLAB + 2097152;
static constexpr size_t OFF_RND  = OFF_RNQ + 65536;
static constexpr size_t OFF_DIAGS= OFF_RND + 65536;
static constexpr size_t OFF_DIAGL= OFF_DIAGS + 65536;
static constexpr size_t OFF_QC   = OFF_DIAGL + 65536;         // bf16 [F][N][RS]
static constexpr size_t OFF_DC   = OFF_QC + (size_t)F * N * RS * 2;

typedef __attribute__((ext_vector_type(8))) short short8;
typedef __attribute__((ext_vector_type(16))) float f32x16;
typedef unsigned long long u64;

__device__ __forceinline__ unsigned fmap(float x) {
    unsigned u = __float_as_uint(x);
    return (u & 0x80000000u) ? ~u : (u | 0x80000000u);
}
__device__ __forceinline__ float bf2f(ushort u) { return __uint_as_float(((unsigned)u) << 16); }
__device__ __forceinline__ ushort f2bf(float x) {
    __hip_bfloat16 h = __float2bfloat16(x);
    return *(ushort*)&h;
}
__device__ __forceinline__ void gload_lds16(const void* g, void* l) {
    __builtin_amdgcn_global_load_lds(
        (const __attribute__((address_space(1))) void*)g,
        (__attribute__((address_space(3))) void*)l, 16, 0, 0);
}

// ---- pack + norms + diag: [2,N,D,F] -> Qc/Dc bf16 [F][N][hi|lo]; fp32 diag ----
__global__ __launch_bounds__(256) void pack_kernel(
    const float* __restrict__ om, const float* __restrict__ label,
    ushort* __restrict__ Qc, ushort* __restrict__ Dc,
    float* __restrict__ rnq, float* __restrict__ rnd,
    float* __restrict__ diag_s, float* __restrict__ diag_l) {
    __shared__ float buf[4][1152];    // [r2*2+side][k*9 + f] padded transpose
    const int i0 = blockIdx.x * 2;
    const int t = threadIdx.x;
#pragma unroll
    for (int s = 0; s < 4; s++) {
        const int r2 = s >> 1, side = s & 1;
        float4 v = *(const float4*)(om + ((size_t)side * N + i0 + r2) * (D * F) + t * 4);
#pragma unroll
        for (int e = 0; e < 4; e++) {
            int g = t * 4 + e;
            buf[s][(g >> 3) * 9 + (g & 7)] = ((const float*)&v)[e];
        }
    }
    __syncthreads();
    const int r2 = t >> 7, f = (t >> 4) & 7, k8 = t & 15;
    float v0[8], v1[8];
#pragma unroll
    for (int j = 0; j < 8; j++) {
        v0[j] = buf[r2 * 2 + 0][(k8 * 8 + j) * 9 + f];
        v1[j] = buf[r2 * 2 + 1][(k8 * 8 + j) * 9 + f];
    }
    short8 H0, L0, H1, L1;
    float s0 = 0.f, s1 = 0.f, p = 0.f;
#pragma unroll
    for (int j = 0; j < 8; j++) {
        ushort h0 = f2bf(v0[j]); ushort l0 = f2bf(v0[j] - bf2f(h0));
        ushort h1 = f2bf(v1[j]); ushort l1 = f2bf(v1[j] - bf2f(h1));
        H0[j] = (short)h0; L0[j] = (short)l0; H1[j] = (short)h1; L1[j] = (short)l1;
        s0 += v0[j] * v0[j]; s1 += v1[j] * v1[j]; p += v0[j] * v1[j];
    }
    const int i = i0 + r2;
    const size_t base = ((size_t)f * N + i) * RS + k8 * 8;
    *(short8*)&Qc[base]       = H0;
    *(short8*)&Qc[base + 128] = L0;
    *(short8*)&Dc[base]       = H1;
    *(short8*)&Dc[base + 128] = L1;
#pragma unroll
    for (int off = 1; off < 16; off <<= 1) {
        s0 += __shfl_xor(s0, off, 64);
        s1 += __shfl_xor(s1, off, 64);
        p  += __shfl_xor(p,  off, 64);
    }
    if (k8 == 0) {
        float rq = 1.0f / sqrtf(s0), rd = 1.0f / sqrtf(s1);
        rnq[f * N + i] = rq;
        rnd[f * N + i] = rd;
        diag_s[f * N + i] = p * rq * rd;
        diag_l[f * N + i] = label[((size_t)f * N + i) * N + i];
    }
}

// ---- fused MFMA GEMM (128x128 tile; wave = 32 rows x 128 cols, 32x32x16) ----
// Fragments: a 1x short8 + b 4x short8 = 20 VGPRs -> fits 64-VGPR budget at
// 4 blocks/CU with 64 AGPR accumulator (R5 spilled here with 40-VGPR frags).
__global__ __launch_bounds__(256, 4) void main_kernel(
    const ushort* __restrict__ Qc, const ushort* __restrict__ Dc,
    const float* __restrict__ label,
    const float* __restrict__ rnq, const float* __restrict__ rnd,
    const float* __restrict__ diag_s, const float* __restrict__ diag_l,
    const float* __restrict__ marginp,
    u64* __restrict__ psim, u64* __restrict__ plab,
    float* __restrict__ loss_acc) {
    __shared__ __align__(16) char smem[32768];  // As[128][64] | Bs[128][64] swizzled
    __shared__ float rowq[128], rowds[128], rowdl[128], colrd[128];
    __shared__ float lred[4];
    ushort* As = (ushort*)smem;
    ushort* Bs = (ushort*)(smem + 16384);

    const int f = blockIdx.z;
    const int i0 = blockIdx.y * 128;
    const int j0 = blockIdx.x * 128;
    const int t = threadIdx.x;
    const int lane = t & 63, wave = t >> 6;
    const int col = lane & 31, half = lane >> 5;
    const int fN = f * N;

    // stage per-row/per-col params into LDS (coalesced; barrier below covers)
    if (t < 128) {
        rowq[t]  = rnq[fN + i0 + t];
        rowds[t] = diag_s[fN + i0 + t];
        rowdl[t] = diag_l[fN + i0 + t];
    } else {
        colrd[t - 128] = rnd[fN + j0 + t - 128];
    }

    f32x16 acc[4];
#pragma unroll
    for (int b = 0; b < 4; b++)
#pragma unroll
        for (int e = 0; e < 16; e++) acc[b][e] = 0.f;

    const char* Ag = (const char*)(Qc + ((size_t)fN + i0) * RS);
    const char* Bg = (const char*)(Dc + ((size_t)fN + j0) * RS);
    char* AsB = smem;
    char* BsB = smem + 16384;
    const int srow = t >> 3, schunk = t & 7;
    // byte offsets into [hi(256B)|lo(256B)] rows: sequence gives hh+hl+lh
    const int qo[6]    = {0, 128, 0, 128, 256, 384};
    const int doffs[6] = {0, 128, 256, 384, 0, 128};
    const int sw = col & 7;   // swizzle key (row&7 == col&7 for fragment rows)

#pragma unroll
    for (int it = 0; it < 6; it++) {
#pragma unroll
        for (int p = 0; p < 4; p++) {
            const int row = srow + p * 32;
            const int gc = schunk ^ (row & 7);
            gload_lds16(Ag + (size_t)row * 512 + qo[it] + gc * 16, AsB + t * 16 + p * 4096);
            gload_lds16(Bg + (size_t)row * 512 + doffs[it] + gc * 16, BsB + t * 16 + p * 4096);
        }
        __syncthreads();   // drains vmcnt -> LDS valid
#pragma unroll
        for (int ks = 0; ks < 4; ks++) {
            const int ck = ks * 2 + half;      // 16B chunk holding this lane's 8 k's
            const int Ra = wave * 32 + col;
            short8 a = *(const short8*)&As[Ra * 64 + ((ck ^ sw) * 8)];
            short8 bf[4];
#pragma unroll
            for (int b = 0; b < 4; b++) {
                const int Rb = b * 32 + col;
                bf[b] = *(const short8*)&Bs[Rb * 64 + ((ck ^ sw) * 8)];
            }
#pragma unroll
            for (int b = 0; b < 4; b++)
                acc[b] = __builtin_amdgcn_mfma_f32_32x32x16_bf16(a, bf[b], acc[b], 0, 0, 0);
        }
        __syncthreads();
    }

    // ---- epilogue: C/D layout col=lane&31, row=(reg&3)+8*(reg>>2)+4*(lane>>5) ----
    const float margin = *marginp;
    float loss = 0.f;
    float rdl[4];
#pragma unroll
    for (int b = 0; b < 4; b++) rdl[b] = colrd[b * 32 + col];

#pragma unroll
    for (int reg = 0; reg < 16; reg++) {
        const int rloc = wave * 32 + (reg & 3) + 8 * (reg >> 2) + 4 * half;
        const int i = i0 + rloc;
        const float rq = rowq[rloc];
        const float ds = rowds[rloc];
        const float dl = rowdl[rloc];
        const float* lrow = label + ((size_t)fN + i) * N + j0;
        u64 bestS = 0ull, bestL = 0ull;
#pragma unroll
        for (int b = 0; b < 4; b++) {
            const int j = j0 + b * 32 + col;
            const float sim = acc[b][reg] * rq * rdl[b];
            const float lb = lrow[b * 32 + col];
            const float lm = margin - (ds - sim) * (dl - lb);
            loss += (j != i && lm > 0.f) ? lm : 0.f;
            u64 ks = (((u64)fmap(sim)) << 32) | (u64)(0xFFFFFFFFu - (unsigned)j);
            u64 kl = (((u64)fmap(lb)) << 32) | (u64)(0xFFFFFFFFu - (unsigned)j);
            bestS = (ks > bestS) ? ks : bestS;
            bestL = (kl > bestL) ? kl : bestL;
        }
        // reduce over the 32 lanes of this half (offsets 1..16 keep bit5)
#pragma unroll
        for (int off = 1; off <= 16; off <<= 1) {
            u64 oS = __shfl_xor(bestS, off, 64);
            u64 oL = __shfl_xor(bestL, off, 64);
            bestS = (oS > bestS) ? oS : bestS;
            bestL = (oL > bestL) ? oL : bestL;
        }
        if (col == 0) {   // lanes 0 and 32 hold final keys for their rows
            psim[(size_t)blockIdx.x * (F * N) + fN + i] = bestS;
            plab[(size_t)blockIdx.x * (F * N) + fN + i] = bestL;
        }
    }

    for (int off = 32; off >= 1; off >>= 1) loss += __shfl_down(loss, off, 64);
    if ((t & 63) == 0) lred[t >> 6] = loss;
    __syncthreads();
    if (t == 0) atomicAdd(loss_acc, lred[0] + lred[1] + lred[2] + lred[3]);
}

// ---- reduce partial keys -> match count ----
__global__ __launch_bounds__(256) void reduce_kernel(
    const u64* __restrict__ psim, const u64* __restrict__ plab, int* __restrict__ cnt) {
    const int r = blockIdx.x * 256 + threadIdx.x;   // 0..F*N-1
    u64 bs = 0ull, bl = 0ull;
#pragma unroll
    for (int jb = 0; jb < 16; jb++) {
        u64 v = psim[(size_t)jb * (F * N) + r]; bs = (v > bs) ? v : bs;
        u64 w = plab[(size_t)jb * (F * N) + r]; bl = (w > bl) ? w : bl;
    }
    int c = ((unsigned)(bs & 0xFFFFFFFFull) == (unsigned)(bl & 0xFFFFFFFFull)) ? 1 : 0;
    for (int off = 32; off >= 1; off >>= 1) c += __shfl_down(c, off, 64);
    __shared__ int cred[4];
    if ((threadIdx.x & 63) == 0) cred[threadIdx.x >> 6] = c;
    __syncthreads();
    if (threadIdx.x == 0) atomicAdd(cnt, cred[0] + cred[1] + cred[2] + cred[3]);
}

__global__ void write_kernel(const float* __restrict__ loss_acc,
                             const int* __restrict__ cnt, float* __restrict__ out) {
    out[0] = *loss_acc;
    out[1] = (float)(*cnt);
}

extern "C" void kernel_launch(void* const* d_in, const int* in_sizes, int n_in,
                              void* d_out, int out_size, void* d_ws, size_t ws_size,
                              hipStream_t stream) {
    const float* om     = (const float*)d_in[0];
    const float* label  = (const float*)d_in[1];
    const float* margin = (const float*)d_in[2];
    (void)in_sizes; (void)n_in; (void)out_size; (void)ws_size;

    char* ws = (char*)d_ws;
    float* loss_acc = (float*)(ws + OFF_LOSS);
    int*   cnt      = (int*)(ws + OFF_CNT);
    u64*   psim     = (u64*)(ws + OFF_PSIM);
    u64*   plab     = (u64*)(ws + OFF_PLAB);
    float* rnq    = (float*)(ws + OFF_RNQ);
    float* rnd    = (float*)(ws + OFF_RND);
    float* diag_s = (float*)(ws + OFF_DIAGS);
    float* diag_l = (float*)(ws + OFF_DIAGL);
    ushort* Qc    = (ushort*)(ws + OFF_QC);
    ushort* Dc    = (ushort*)(ws + OFF_DC);

    hipMemsetAsync(ws, 0, 8, stream);   // loss + count only

    pack_kernel<<<N / 2, 256, 0, stream>>>(om, label, Qc, Dc, rnq, rnd, diag_s, diag_l);

    dim3 grid(N / 128, N / 128, F);
    main_kernel<<<grid, 256, 0, stream>>>(Qc, Dc, label, rnq, rnd, diag_s, diag_l,
                                          margin, psim, plab, loss_acc);

    reduce_kernel<<<F * N / 256, 256, 0, stream>>>(psim, plab, cnt);
    write_kernel<<<1, 1, 0, stream>>>(loss_acc, cnt, (float*)d_out);
}

// Round 7
// 296.391 us; speedup vs baseline: 1.0864x; 1.0864x over previous
//
#include <hip/hip_runtime.h>
#include <hip/hip_bf16.h>

static constexpr int N = 2048;
static constexpr int D = 128;
static constexpr int F = 8;
static constexpr int RS = 256;   // packed row stride (ushorts): [hi(128) | lo(128)]

// ---------------- workspace layout (bytes) ----------------
static constexpr size_t OFF_LOSS = 0;        // float
static constexpr size_t OFF_CNT  = 4;        // int
static constexpr size_t OFF_PSIM = 1024;                      // u64 [16][F*N] partial sim keys
static constexpr size_t OFF_PLAB = 1024 + 2097152;            // u64 [16][F*N]
static constexpr size_t OFF_RNQ  = OFF_PLAB + 2097152;
static constexpr size_t OFF_RND  = OFF_RNQ + 65536;
static constexpr size_t OFF_DIAGS= OFF_RND + 65536;
static constexpr size_t OFF_DIAGL= OFF_DIAGS + 65536;
static constexpr size_t OFF_QC   = OFF_DIAGL + 65536;         // bf16 [F][N][RS]
static constexpr size_t OFF_DC   = OFF_QC + (size_t)F * N * RS * 2;

typedef __attribute__((ext_vector_type(8))) short short8;
typedef __attribute__((ext_vector_type(4))) float f32x4;
typedef unsigned long long u64;

__device__ __forceinline__ unsigned fmap(float x) {
    unsigned u = __float_as_uint(x);
    return (u & 0x80000000u) ? ~u : (u | 0x80000000u);
}
__device__ __forceinline__ float bf2f(ushort u) { return __uint_as_float(((unsigned)u) << 16); }
__device__ __forceinline__ ushort f2bf(float x) {
    __hip_bfloat16 h = __float2bfloat16(x);
    return *(ushort*)&h;
}
__device__ __forceinline__ void gload_lds16(const void* g, void* l) {
    __builtin_amdgcn_global_load_lds(
        (const __attribute__((address_space(1))) void*)g,
        (__attribute__((address_space(3))) void*)l, 16, 0, 0);
}

// ---- pack + norms + diag: [2,N,D,F] -> Qc/Dc bf16 [F][N][hi|lo]; fp32 diag ----
__global__ __launch_bounds__(256) void pack_kernel(
    const float* __restrict__ om, const float* __restrict__ label,
    ushort* __restrict__ Qc, ushort* __restrict__ Dc,
    float* __restrict__ rnq, float* __restrict__ rnd,
    float* __restrict__ diag_s, float* __restrict__ diag_l) {
    __shared__ float buf[4][1152];    // [r2*2+side][k*9 + f] padded transpose
    const int i0 = blockIdx.x * 2;
    const int t = threadIdx.x;
#pragma unroll
    for (int s = 0; s < 4; s++) {
        const int r2 = s >> 1, side = s & 1;
        float4 v = *(const float4*)(om + ((size_t)side * N + i0 + r2) * (D * F) + t * 4);
#pragma unroll
        for (int e = 0; e < 4; e++) {
            int g = t * 4 + e;
            buf[s][(g >> 3) * 9 + (g & 7)] = ((const float*)&v)[e];
        }
    }
    __syncthreads();
    const int r2 = t >> 7, f = (t >> 4) & 7, k8 = t & 15;
    float v0[8], v1[8];
#pragma unroll
    for (int j = 0; j < 8; j++) {
        v0[j] = buf[r2 * 2 + 0][(k8 * 8 + j) * 9 + f];
        v1[j] = buf[r2 * 2 + 1][(k8 * 8 + j) * 9 + f];
    }
    short8 H0, L0, H1, L1;
    float s0 = 0.f, s1 = 0.f, p = 0.f;
#pragma unroll
    for (int j = 0; j < 8; j++) {
        ushort h0 = f2bf(v0[j]); ushort l0 = f2bf(v0[j] - bf2f(h0));
        ushort h1 = f2bf(v1[j]); ushort l1 = f2bf(v1[j] - bf2f(h1));
        H0[j] = (short)h0; L0[j] = (short)l0; H1[j] = (short)h1; L1[j] = (short)l1;
        s0 += v0[j] * v0[j]; s1 += v1[j] * v1[j]; p += v0[j] * v1[j];
    }
    const int i = i0 + r2;
    const size_t base = ((size_t)f * N + i) * RS + k8 * 8;
    *(short8*)&Qc[base]       = H0;
    *(short8*)&Qc[base + 128] = L0;
    *(short8*)&Dc[base]       = H1;
    *(short8*)&Dc[base + 128] = L1;
#pragma unroll
    for (int off = 1; off < 16; off <<= 1) {
        s0 += __shfl_xor(s0, off, 64);
        s1 += __shfl_xor(s1, off, 64);
        p  += __shfl_xor(p,  off, 64);
    }
    if (k8 == 0) {
        float rq = 1.0f / sqrtf(s0), rd = 1.0f / sqrtf(s1);
        rnq[f * N + i] = rq;
        rnd[f * N + i] = rd;
        diag_s[f * N + i] = p * rq * rd;
        diag_l[f * N + i] = label[((size_t)f * N + i) * N + i];
    }
}

// ---- fused MFMA GEMM (128x128 tile; wave = 32 rows x 128 cols) + epilogue ----
// LDS rows are 128B; 16B chunk position XOR-swizzled by (row&7) -> conflict-free
// (R3/R5 measured SQ_LDS_BANK_CONFLICT == 0).
// __launch_bounds__(256,3): 170 regs/wave = 64 AGPR acc + ~100 arch VGPRs.
// NOTE: (256,4) spills (R5: 94 MB scratch) -- AGPRs count against the budget.
__global__ __launch_bounds__(256, 3) void main_kernel(
    const ushort* __restrict__ Qc, const ushort* __restrict__ Dc,
    const float* __restrict__ label,
    const float* __restrict__ rnq, const float* __restrict__ rnd,
    const float* __restrict__ diag_s, const float* __restrict__ diag_l,
    const float* __restrict__ marginp,
    u64* __restrict__ psim, u64* __restrict__ plab,
    float* __restrict__ loss_acc) {
    __shared__ __align__(16) char smem[34816];
    ushort* As = (ushort*)smem;            // [128][64] swizzled
    ushort* Bs = (ushort*)(smem + 16384);
    u64* kbS = (u64*)smem;                 // [128][17] overlay (post K-loop)
    u64* kbL = (u64*)(smem + 17408);
    __shared__ float lred[4];

    const int f = blockIdx.z;
    const int i0 = blockIdx.y * 128;
    const int j0 = blockIdx.x * 128;
    const int t = threadIdx.x;
    const int lane = t & 63, wave = t >> 6;
    const int lhi = lane >> 4, llo = lane & 15;

    f32x4 acc[2][8];
#pragma unroll
    for (int a = 0; a < 2; a++)
#pragma unroll
        for (int b = 0; b < 8; b++) acc[a][b] = (f32x4){0.f, 0.f, 0.f, 0.f};

    const char* Ag = (const char*)(Qc + ((size_t)f * N + i0) * RS);
    const char* Bg = (const char*)(Dc + ((size_t)f * N + j0) * RS);
    char* AsB = smem;
    char* BsB = smem + 16384;
    const int srow = t >> 3, schunk = t & 7;
    // byte offsets into [hi(256B)|lo(256B)] rows: sequence gives hh+hl+lh
    const int qo[6]    = {0, 128, 0, 128, 256, 384};
    const int doffs[6] = {0, 128, 256, 384, 0, 128};

#pragma unroll
    for (int it = 0; it < 6; it++) {
#pragma unroll
        for (int p = 0; p < 4; p++) {
            const int row = srow + p * 32;
            const int gc = schunk ^ (row & 7);
            gload_lds16(Ag + (size_t)row * 512 + qo[it] + gc * 16, AsB + t * 16 + p * 4096);
            gload_lds16(Bg + (size_t)row * 512 + doffs[it] + gc * 16, BsB + t * 16 + p * 4096);
        }
        __syncthreads();   // drains vmcnt -> LDS valid
#pragma unroll
        for (int kk = 0; kk < 64; kk += 32) {
            const int kc = kk >> 3;
            short8 af[2], bfv[8];
#pragma unroll
            for (int a = 0; a < 2; a++) {
                const int R = wave * 32 + a * 16 + llo;
                af[a] = *(const short8*)&As[R * 64 + (((kc + lhi) ^ (R & 7)) * 8)];
            }
#pragma unroll
            for (int b = 0; b < 8; b++) {
                const int R = b * 16 + llo;
                bfv[b] = *(const short8*)&Bs[R * 64 + (((kc + lhi) ^ (R & 7)) * 8)];
            }
#pragma unroll
            for (int a = 0; a < 2; a++)
#pragma unroll
                for (int b = 0; b < 8; b++)
                    acc[a][b] = __builtin_amdgcn_mfma_f32_16x16x32_bf16(af[a], bfv[b], acc[a][b], 0, 0, 0);
        }
        __syncthreads();
    }

    // -------- epilogue: C/D layout col=lane&15, row=(lane>>4)*4+reg --------
    const float margin = *marginp;
    float loss = 0.f;
    float rdl[8];
#pragma unroll
    for (int b = 0; b < 8; b++) rdl[b] = rnd[f * N + j0 + b * 16 + llo];

#pragma unroll
    for (int a = 0; a < 2; a++) {
#pragma unroll
        for (int reg = 0; reg < 4; reg++) {
            const int rloc = wave * 32 + a * 16 + lhi * 4 + reg;
            const int i = i0 + rloc;
            const float rq = rnq[f * N + i];
            const float ds = diag_s[f * N + i];
            const float dl = diag_l[f * N + i];
            const float* lrow = label + ((size_t)f * N + i) * N + j0;
            u64 bestS = 0ull, bestL = 0ull;
#pragma unroll
            for (int b = 0; b < 8; b++) {
                const int j = j0 + b * 16 + llo;
                const float sim = acc[a][b][reg] * rq * rdl[b];
                const float lb = lrow[b * 16 + llo];
                const float lm = margin - (ds - sim) * (dl - lb);
                loss += (j != i && lm > 0.f) ? lm : 0.f;
                u64 ks = (((u64)fmap(sim)) << 32) | (u64)(0xFFFFFFFFu - (unsigned)j);
                u64 kl = (((u64)fmap(lb)) << 32) | (u64)(0xFFFFFFFFu - (unsigned)j);
                bestS = (ks > bestS) ? ks : bestS;
                bestL = (kl > bestL) ? kl : bestL;
            }
            kbS[rloc * 17 + llo] = bestS;
            kbL[rloc * 17 + llo] = bestL;
        }
    }
    __syncthreads();
    {   // plain coalesced partial-key stores (no atomics, no init needed)
        const int r = t & 127;
        const u64* kb = (t < 128) ? kbS : kbL;
        u64 best = 0ull;
#pragma unroll
        for (int k = 0; k < 16; k++) {
            u64 v = kb[r * 17 + k];
            best = (v > best) ? v : best;
        }
        u64* dst = (t < 128) ? psim : plab;
        dst[(size_t)blockIdx.x * (F * N) + f * N + i0 + r] = best;
    }

    for (int off = 32; off >= 1; off >>= 1) loss += __shfl_down(loss, off, 64);
    if ((t & 63) == 0) lred[t >> 6] = loss;
    __syncthreads();
    if (t == 0) atomicAdd(loss_acc, lred[0] + lred[1] + lred[2] + lred[3]);
}

// ---- reduce partial keys -> match count; last block writes outputs ----
__global__ __launch_bounds__(256) void reduce_kernel(
    const u64* __restrict__ psim, const u64* __restrict__ plab,
    int* __restrict__ cnt, const float* __restrict__ loss_acc,
    float* __restrict__ out) {
    const int r = blockIdx.x * 256 + threadIdx.x;   // 0..F*N-1
    u64 bs = 0ull, bl = 0ull;
#pragma unroll
    for (int jb = 0; jb < 16; jb++) {
        u64 v = psim[(size_t)jb * (F * N) + r]; bs = (v > bs) ? v : bs;
        u64 w = plab[(size_t)jb * (F * N) + r]; bl = (w > bl) ? w : bl;
    }
    int c = ((unsigned)(bs & 0xFFFFFFFFull) == (unsigned)(bl & 0xFFFFFFFFull)) ? 1 : 0;
    for (int off = 32; off >= 1; off >>= 1) c += __shfl_down(c, off, 64);
    __shared__ int cred[4];
    __shared__ int isLast;
    if ((threadIdx.x & 63) == 0) cred[threadIdx.x >> 6] = c;
    __syncthreads();
    if (threadIdx.x == 0) {
        int total = atomicAdd(cnt, cred[0] + cred[1] + cred[2] + cred[3]);
        __threadfence();
        // cnt[1] counts finished blocks (zeroed by memset)
        int done = atomicAdd(cnt + 1, 1);
        isLast = (done == (int)gridDim.x - 1);
        (void)total;
    }
    __syncthreads();
    if (isLast && threadIdx.x == 0) {
        __threadfence();
        out[0] = *loss_acc;
        out[1] = (float)(*(volatile int*)cnt);
    }
}

extern "C" void kernel_launch(void* const* d_in, const int* in_sizes, int n_in,
                              void* d_out, int out_size, void* d_ws, size_t ws_size,
                              hipStream_t stream) {
    const float* om     = (const float*)d_in[0];
    const float* label  = (const float*)d_in[1];
    const float* margin = (const float*)d_in[2];
    (void)in_sizes; (void)n_in; (void)out_size; (void)ws_size;

    char* ws = (char*)d_ws;
    float* loss_acc = (float*)(ws + OFF_LOSS);
    int*   cnt      = (int*)(ws + OFF_CNT);
    u64*   psim     = (u64*)(ws + OFF_PSIM);
    u64*   plab     = (u64*)(ws + OFF_PLAB);
    float* rnq    = (float*)(ws + OFF_RNQ);
    float* rnd    = (float*)(ws + OFF_RND);
    float* diag_s = (float*)(ws + OFF_DIAGS);
    float* diag_l = (float*)(ws + OFF_DIAGL);
    ushort* Qc    = (ushort*)(ws + OFF_QC);
    ushort* Dc    = (ushort*)(ws + OFF_DC);

    hipMemsetAsync(ws, 0, 16, stream);   // loss + count + done-counter

    pack_kernel<<<N / 2, 256, 0, stream>>>(om, label, Qc, Dc, rnq, rnd, diag_s, diag_l);

    dim3 grid(N / 128, N / 128, F);
    main_kernel<<<grid, 256, 0, stream>>>(Qc, Dc, label, rnq, rnd, diag_s, diag_l,
                                          margin, psim, plab, loss_acc);

    reduce_kernel<<<F * N / 256, 256, 0, stream>>>(psim, plab, cnt, loss_acc, (float*)d_out);
}

// Round 8
// 230.242 us; speedup vs baseline: 1.3986x; 1.2873x over previous
//
#include <hip/hip_runtime.h>
#include <hip/hip_bf16.h>

static constexpr int N = 2048;
static constexpr int D = 128;
static constexpr int F = 8;

// ---------------- workspace layout (bytes) ----------------
static constexpr size_t OFF_LOSS = 0;        // float
static constexpr size_t OFF_CNT  = 4;        // int cnt + int done-counter
static constexpr size_t OFF_PSIM = 1024;                      // u64 [16][F*N]
static constexpr size_t OFF_PLAB = 1024 + 2097152;            // u64 [16][F*N]
static constexpr size_t OFF_RNQ  = OFF_PLAB + 2097152;
static constexpr size_t OFF_RND  = OFF_RNQ + 65536;
static constexpr size_t OFF_DIAGS= OFF_RND + 65536;
static constexpr size_t OFF_DIAGL= OFF_DIAGS + 65536;
static constexpr size_t OFF_QH   = OFF_DIAGL + 65536;         // f16 [F][N][128]
static constexpr size_t OFF_DH   = OFF_QH + (size_t)F * N * D * 2;

typedef _Float16 half8 __attribute__((ext_vector_type(8)));
typedef __attribute__((ext_vector_type(4))) float f32x4;
typedef unsigned long long u64;

__device__ __forceinline__ unsigned fmap(float x) {
    unsigned u = __float_as_uint(x);
    return (u & 0x80000000u) ? ~u : (u | 0x80000000u);
}
__device__ __forceinline__ void gload_lds16(const void* g, void* l) {
    __builtin_amdgcn_global_load_lds(
        (const __attribute__((address_space(1))) void*)g,
        (__attribute__((address_space(3))) void*)l, 16, 0, 0);
}

// ---- pack + norms + diag: [2,N,D,F] -> Qh/Dh f16 [F][N][128]; fp32 diag ----
__global__ __launch_bounds__(256) void pack_kernel(
    const float* __restrict__ om, const float* __restrict__ label,
    _Float16* __restrict__ Qh, _Float16* __restrict__ Dh,
    float* __restrict__ rnq, float* __restrict__ rnd,
    float* __restrict__ diag_s, float* __restrict__ diag_l) {
    __shared__ float buf[4][1152];    // [r2*2+side][k*9 + f] padded transpose
    const int i0 = blockIdx.x * 2;
    const int t = threadIdx.x;
#pragma unroll
    for (int s = 0; s < 4; s++) {
        const int r2 = s >> 1, side = s & 1;
        float4 v = *(const float4*)(om + ((size_t)side * N + i0 + r2) * (D * F) + t * 4);
#pragma unroll
        for (int e = 0; e < 4; e++) {
            int g = t * 4 + e;
            buf[s][(g >> 3) * 9 + (g & 7)] = ((const float*)&v)[e];
        }
    }
    __syncthreads();
    const int r2 = t >> 7, f = (t >> 4) & 7, k8 = t & 15;
    float v0[8], v1[8];
#pragma unroll
    for (int j = 0; j < 8; j++) {
        v0[j] = buf[r2 * 2 + 0][(k8 * 8 + j) * 9 + f];
        v1[j] = buf[r2 * 2 + 1][(k8 * 8 + j) * 9 + f];
    }
    half8 H0, H1;
    float s0 = 0.f, s1 = 0.f, p = 0.f;
#pragma unroll
    for (int j = 0; j < 8; j++) {
        H0[j] = (_Float16)v0[j];
        H1[j] = (_Float16)v1[j];
        s0 += v0[j] * v0[j]; s1 += v1[j] * v1[j]; p += v0[j] * v1[j];
    }
    const int i = i0 + r2;
    const size_t base = ((size_t)f * N + i) * D + k8 * 8;
    *(half8*)&Qh[base] = H0;
    *(half8*)&Dh[base] = H1;
#pragma unroll
    for (int off = 1; off < 16; off <<= 1) {
        s0 += __shfl_xor(s0, off, 64);
        s1 += __shfl_xor(s1, off, 64);
        p  += __shfl_xor(p,  off, 64);
    }
    if (k8 == 0) {
        float rq = 1.0f / sqrtf(s0), rd = 1.0f / sqrtf(s1);
        rnq[f * N + i] = rq;
        rnd[f * N + i] = rd;
        diag_s[f * N + i] = p * rq * rd;
        diag_l[f * N + i] = label[((size_t)f * N + i) * N + i];
    }
}

// ---- fused f16 MFMA GEMM (128x128 tile, K=128 in ONE staging phase) ----
// LDS rows are 256B (128 f16); 16B chunk position XOR-swizzled by (row&15)
// -> fragment ds_read_b128 is 2-way only (free, m136).  One __syncthreads
// in the whole matmul.  (256,2): 256 unified regs/wave -> spill impossible.
__global__ __launch_bounds__(256, 2) void main_kernel(
    const _Float16* __restrict__ Qh, const _Float16* __restrict__ Dh,
    const float* __restrict__ label,
    const float* __restrict__ rnq, const float* __restrict__ rnd,
    const float* __restrict__ diag_s, const float* __restrict__ diag_l,
    const float* __restrict__ marginp,
    u64* __restrict__ psim, u64* __restrict__ plab,
    float* __restrict__ loss_acc) {
    __shared__ __align__(16) char smem[65536];
    _Float16* As = (_Float16*)smem;            // [128][128] swizzled
    _Float16* Bs = (_Float16*)(smem + 32768);
    u64* kbS = (u64*)smem;                     // [128][17] overlay (post-GEMM)
    u64* kbL = (u64*)(smem + 17408);
    __shared__ float lred[4];

    const int f = blockIdx.z;
    const int i0 = blockIdx.y * 128;
    const int j0 = blockIdx.x * 128;
    const int t = threadIdx.x;
    const int lane = t & 63, wave = t >> 6;
    const int lhi = lane >> 4, llo = lane & 15;

    f32x4 acc[2][8];
#pragma unroll
    for (int a = 0; a < 2; a++)
#pragma unroll
        for (int b = 0; b < 8; b++) acc[a][b] = (f32x4){0.f, 0.f, 0.f, 0.f};

    const char* Ag = (const char*)(Qh + ((size_t)f * N + i0) * D);
    const char* Bg = (const char*)(Dh + ((size_t)f * N + j0) * D);
    char* AsB = smem;
    char* BsB = smem + 32768;
    const int srow = t >> 4, schunk = t & 15;

#pragma unroll
    for (int p = 0; p < 8; p++) {
        const int row = srow + p * 16;
        const int gc = schunk ^ (row & 15);
        gload_lds16(Ag + (size_t)row * 256 + gc * 16, AsB + t * 16 + p * 4096);
        gload_lds16(Bg + (size_t)row * 256 + gc * 16, BsB + t * 16 + p * 4096);
    }
    __syncthreads();   // drains vmcnt -> LDS valid (the ONLY matmul barrier)

#pragma unroll
    for (int kk = 0; kk < 128; kk += 32) {
        const int kc = kk >> 3;
        half8 af[2], bfv[8];
#pragma unroll
        for (int a = 0; a < 2; a++) {
            const int R = wave * 32 + a * 16 + llo;
            af[a] = *(const half8*)&As[R * 128 + (((kc + lhi) ^ (R & 15)) * 8)];
        }
#pragma unroll
        for (int b = 0; b < 8; b++) {
            const int R = b * 16 + llo;
            bfv[b] = *(const half8*)&Bs[R * 128 + (((kc + lhi) ^ (R & 15)) * 8)];
        }
#pragma unroll
        for (int a = 0; a < 2; a++)
#pragma unroll
            for (int b = 0; b < 8; b++)
                acc[a][b] = __builtin_amdgcn_mfma_f32_16x16x32_f16(af[a], bfv[b], acc[a][b], 0, 0, 0);
    }

    // -------- epilogue: C/D layout col=lane&15, row=(lane>>4)*4+reg --------
    const float margin = *marginp;
    float loss = 0.f;
    float rdl[8];
#pragma unroll
    for (int b = 0; b < 8; b++) rdl[b] = rnd[f * N + j0 + b * 16 + llo];

    __syncthreads();   // LDS buffers free -> reuse as key boards
#pragma unroll
    for (int a = 0; a < 2; a++) {
#pragma unroll
        for (int reg = 0; reg < 4; reg++) {
            const int rloc = wave * 32 + a * 16 + lhi * 4 + reg;
            const int i = i0 + rloc;
            const float rq = rnq[f * N + i];
            const float ds = diag_s[f * N + i];
            const float dl = diag_l[f * N + i];
            const float* lrow = label + ((size_t)f * N + i) * N + j0;
            u64 bestS = 0ull, bestL = 0ull;
#pragma unroll
            for (int b = 0; b < 8; b++) {
                const int j = j0 + b * 16 + llo;
                const float sim = acc[a][b][reg] * rq * rdl[b];
                const float lb = lrow[b * 16 + llo];
                const float lm = margin - (ds - sim) * (dl - lb);
                loss += (j != i && lm > 0.f) ? lm : 0.f;
                u64 ks = (((u64)fmap(sim)) << 32) | (u64)(0xFFFFFFFFu - (unsigned)j);
                u64 kl = (((u64)fmap(lb)) << 32) | (u64)(0xFFFFFFFFu - (unsigned)j);
                bestS = (ks > bestS) ? ks : bestS;
                bestL = (kl > bestL) ? kl : bestL;
            }
            kbS[rloc * 17 + llo] = bestS;
            kbL[rloc * 17 + llo] = bestL;
        }
    }
    __syncthreads();
    {   // plain coalesced partial-key stores (no atomics, no init needed)
        const int r = t & 127;
        const u64* kb = (t < 128) ? kbS : kbL;
        u64 best = 0ull;
#pragma unroll
        for (int k = 0; k < 16; k++) {
            u64 v = kb[r * 17 + k];
            best = (v > best) ? v : best;
        }
        u64* dst = (t < 128) ? psim : plab;
        dst[(size_t)blockIdx.x * (F * N) + f * N + i0 + r] = best;
    }

    for (int off = 32; off >= 1; off >>= 1) loss += __shfl_down(loss, off, 64);
    if ((t & 63) == 0) lred[t >> 6] = loss;
    __syncthreads();
    if (t == 0) atomicAdd(loss_acc, lred[0] + lred[1] + lred[2] + lred[3]);
}

// ---- reduce partial keys -> match count; last block writes outputs ----
__global__ __launch_bounds__(256) void reduce_kernel(
    const u64* __restrict__ psim, const u64* __restrict__ plab,
    int* __restrict__ cnt, const float* __restrict__ loss_acc,
    float* __restrict__ out) {
    const int r = blockIdx.x * 256 + threadIdx.x;   // 0..F*N-1
    u64 bs = 0ull, bl = 0ull;
#pragma unroll
    for (int jb = 0; jb < 16; jb++) {
        u64 v = psim[(size_t)jb * (F * N) + r]; bs = (v > bs) ? v : bs;
        u64 w = plab[(size_t)jb * (F * N) + r]; bl = (w > bl) ? w : bl;
    }
    int c = ((unsigned)(bs & 0xFFFFFFFFull) == (unsigned)(bl & 0xFFFFFFFFull)) ? 1 : 0;
    for (int off = 32; off >= 1; off >>= 1) c += __shfl_down(c, off, 64);
    __shared__ int cred[4];
    __shared__ int isLast;
    if ((threadIdx.x & 63) == 0) cred[threadIdx.x >> 6] = c;
    __syncthreads();
    if (threadIdx.x == 0) {
        atomicAdd(cnt, cred[0] + cred[1] + cred[2] + cred[3]);
        __threadfence();
        int done = atomicAdd(cnt + 1, 1);
        isLast = (done == (int)gridDim.x - 1);
    }
    __syncthreads();
    if (isLast && threadIdx.x == 0) {
        __threadfence();
        out[0] = *loss_acc;
        out[1] = (float)(*(volatile int*)cnt);
    }
}

extern "C" void kernel_launch(void* const* d_in, const int* in_sizes, int n_in,
                              void* d_out, int out_size, void* d_ws, size_t ws_size,
                              hipStream_t stream) {
    const float* om     = (const float*)d_in[0];
    const float* label  = (const float*)d_in[1];
    const float* margin = (const float*)d_in[2];
    (void)in_sizes; (void)n_in; (void)out_size; (void)ws_size;

    char* ws = (char*)d_ws;
    float* loss_acc = (float*)(ws + OFF_LOSS);
    int*   cnt      = (int*)(ws + OFF_CNT);
    u64*   psim     = (u64*)(ws + OFF_PSIM);
    u64*   plab     = (u64*)(ws + OFF_PLAB);
    float* rnq    = (float*)(ws + OFF_RNQ);
    float* rnd    = (float*)(ws + OFF_RND);
    float* diag_s = (float*)(ws + OFF_DIAGS);
    float* diag_l = (float*)(ws + OFF_DIAGL);
    _Float16* Qh  = (_Float16*)(ws + OFF_QH);
    _Float16* Dh  = (_Float16*)(ws + OFF_DH);

    hipMemsetAsync(ws, 0, 16, stream);   // loss + count + done-counter

    pack_kernel<<<N / 2, 256, 0, stream>>>(om, label, Qh, Dh, rnq, rnd, diag_s, diag_l);

    dim3 grid(N / 128, N / 128, F);
    main_kernel<<<grid, 256, 0, stream>>>(Qh, Dh, label, rnq, rnd, diag_s, diag_l,
                                          margin, psim, plab, loss_acc);

    reduce_kernel<<<F * N / 256, 256, 0, stream>>>(psim, plab, cnt, loss_acc, (float*)d_out);
}

// Round 9
// 221.759 us; speedup vs baseline: 1.4521x; 1.0383x over previous
//
#include <hip/hip_runtime.h>
#include <hip/hip_bf16.h>

static constexpr int N = 2048;
static constexpr int D = 128;
static constexpr int F = 8;

// ---------------- workspace layout (bytes) ----------------
static constexpr size_t OFF_LOSS = 0;        // float
static constexpr size_t OFF_CNT  = 4;        // int cnt + int done-counter (+pad)
static constexpr size_t OFF_PSIM = 1024;                      // u64 [16][F*N]
static constexpr size_t OFF_PLAB = 1024 + 2097152;            // u64 [16][F*N]
static constexpr size_t OFF_RNQ  = OFF_PLAB + 2097152;
static constexpr size_t OFF_RND  = OFF_RNQ + 65536;
static constexpr size_t OFF_DIAGS= OFF_RND + 65536;
static constexpr size_t OFF_DIAGL= OFF_DIAGS + 65536;
static constexpr size_t OFF_QH   = OFF_DIAGL + 65536;         // f16 [F][N][128]
static constexpr size_t OFF_DH   = OFF_QH + (size_t)F * N * D * 2;

typedef _Float16 half8 __attribute__((ext_vector_type(8)));
typedef __attribute__((ext_vector_type(4))) float f32x4;
typedef unsigned long long u64;

__device__ __forceinline__ unsigned fmap(float x) {
    unsigned u = __float_as_uint(x);
    return (u & 0x80000000u) ? ~u : (u | 0x80000000u);
}
__device__ __forceinline__ void gload_lds16(const void* g, void* l) {
    __builtin_amdgcn_global_load_lds(
        (const __attribute__((address_space(1))) void*)g,
        (__attribute__((address_space(3))) void*)l, 16, 0, 0);
}

// ---- pack + norms + diag: [2,N,D,F] -> Qh/Dh f16 [F][N][128]; fp32 diag ----
// Block 0 also zeroes the ws header (loss/cnt/done) -- replaces a memset dispatch.
__global__ __launch_bounds__(256) void pack_kernel(
    const float* __restrict__ om, const float* __restrict__ label,
    _Float16* __restrict__ Qh, _Float16* __restrict__ Dh,
    float* __restrict__ rnq, float* __restrict__ rnd,
    float* __restrict__ diag_s, float* __restrict__ diag_l,
    int* __restrict__ hdr) {
    __shared__ float buf[4][1152];    // [r2*2+side][k*9 + f] padded transpose
    const int i0 = blockIdx.x * 2;
    const int t = threadIdx.x;
    if (blockIdx.x == 0 && t < 4) hdr[t] = 0;
#pragma unroll
    for (int s = 0; s < 4; s++) {
        const int r2 = s >> 1, side = s & 1;
        float4 v = *(const float4*)(om + ((size_t)side * N + i0 + r2) * (D * F) + t * 4);
#pragma unroll
        for (int e = 0; e < 4; e++) {
            int g = t * 4 + e;
            buf[s][(g >> 3) * 9 + (g & 7)] = ((const float*)&v)[e];
        }
    }
    __syncthreads();
    const int r2 = t >> 7, f = (t >> 4) & 7, k8 = t & 15;
    float v0[8], v1[8];
#pragma unroll
    for (int j = 0; j < 8; j++) {
        v0[j] = buf[r2 * 2 + 0][(k8 * 8 + j) * 9 + f];
        v1[j] = buf[r2 * 2 + 1][(k8 * 8 + j) * 9 + f];
    }
    half8 H0, H1;
    float s0 = 0.f, s1 = 0.f, p = 0.f;
#pragma unroll
    for (int j = 0; j < 8; j++) {
        H0[j] = (_Float16)v0[j];
        H1[j] = (_Float16)v1[j];
        s0 += v0[j] * v0[j]; s1 += v1[j] * v1[j]; p += v0[j] * v1[j];
    }
    const int i = i0 + r2;
    const size_t base = ((size_t)f * N + i) * D + k8 * 8;
    *(half8*)&Qh[base] = H0;
    *(half8*)&Dh[base] = H1;
#pragma unroll
    for (int off = 1; off < 16; off <<= 1) {
        s0 += __shfl_xor(s0, off, 64);
        s1 += __shfl_xor(s1, off, 64);
        p  += __shfl_xor(p,  off, 64);
    }
    if (k8 == 0) {
        float rq = 1.0f / sqrtf(s0), rd = 1.0f / sqrtf(s1);
        rnq[f * N + i] = rq;
        rnd[f * N + i] = rd;
        diag_s[f * N + i] = p * rq * rd;
        diag_l[f * N + i] = label[((size_t)f * N + i) * N + i];
    }
}

// ---- fused f16 MFMA GEMM (128x128 tile, K=128 in ONE staging phase) ----
// Sim path is bit-identical to R8 (fixed-seed argmax verified absmax==0).
// New in R9: 64-float register label prefetch issued before the barrier
// (fully unrolled, no guards -> stays in VGPRs; ~198/256 regs at (256,2)),
// branchless diagonal (term == margin exactly; subtracted in reduce),
// 1-op label key (labels >= 0).
__global__ __launch_bounds__(256, 2) void main_kernel(
    const _Float16* __restrict__ Qh, const _Float16* __restrict__ Dh,
    const float* __restrict__ label,
    const float* __restrict__ rnq, const float* __restrict__ rnd,
    const float* __restrict__ diag_s, const float* __restrict__ diag_l,
    const float* __restrict__ marginp,
    u64* __restrict__ psim, u64* __restrict__ plab,
    float* __restrict__ loss_acc) {
    __shared__ __align__(16) char smem[65536];
    _Float16* As = (_Float16*)smem;            // [128][128] swizzled
    _Float16* Bs = (_Float16*)(smem + 32768);
    u64* kbS = (u64*)smem;                     // [128][17] overlay (post-GEMM)
    u64* kbL = (u64*)(smem + 17408);
    __shared__ float lred[4];

    const int f = blockIdx.z;
    const int i0 = blockIdx.y * 128;
    const int j0 = blockIdx.x * 128;
    const int t = threadIdx.x;
    const int lane = t & 63, wave = t >> 6;
    const int lhi = lane >> 4, llo = lane & 15;

    f32x4 acc[2][8];
#pragma unroll
    for (int a = 0; a < 2; a++)
#pragma unroll
        for (int b = 0; b < 8; b++) acc[a][b] = (f32x4){0.f, 0.f, 0.f, 0.f};

    const char* Ag = (const char*)(Qh + ((size_t)f * N + i0) * D);
    const char* Bg = (const char*)(Dh + ((size_t)f * N + j0) * D);
    char* AsB = smem;
    char* BsB = smem + 32768;
    const int srow = t >> 4, schunk = t & 15;

    // label prefetch: in flight during staging + GEMM
    float lab[2][4][8];
#pragma unroll
    for (int a = 0; a < 2; a++)
#pragma unroll
        for (int reg = 0; reg < 4; reg++) {
            const int rloc = wave * 32 + a * 16 + lhi * 4 + reg;
            const float* lrow = label + ((size_t)(f * N + i0 + rloc)) * N + j0 + llo;
#pragma unroll
            for (int b = 0; b < 8; b++) lab[a][reg][b] = lrow[b * 16];
        }

#pragma unroll
    for (int p = 0; p < 8; p++) {
        const int row = srow + p * 16;
        const int gc = schunk ^ (row & 15);
        gload_lds16(Ag + (size_t)row * 256 + gc * 16, AsB + t * 16 + p * 4096);
        gload_lds16(Bg + (size_t)row * 256 + gc * 16, BsB + t * 16 + p * 4096);
    }
    __syncthreads();   // drains vmcnt -> LDS valid (the ONLY matmul barrier)

#pragma unroll
    for (int kk = 0; kk < 128; kk += 32) {
        const int kc = kk >> 3;
        half8 af[2], bfv[8];
#pragma unroll
        for (int a = 0; a < 2; a++) {
            const int R = wave * 32 + a * 16 + llo;
            af[a] = *(const half8*)&As[R * 128 + (((kc + lhi) ^ (R & 15)) * 8)];
        }
#pragma unroll
        for (int b = 0; b < 8; b++) {
            const int R = b * 16 + llo;
            bfv[b] = *(const half8*)&Bs[R * 128 + (((kc + lhi) ^ (R & 15)) * 8)];
        }
#pragma unroll
        for (int a = 0; a < 2; a++)
#pragma unroll
            for (int b = 0; b < 8; b++)
                acc[a][b] = __builtin_amdgcn_mfma_f32_16x16x32_f16(af[a], bfv[b], acc[a][b], 0, 0, 0);
    }

    // -------- epilogue: C/D layout col=lane&15, row=(lane>>4)*4+reg --------
    const float margin = *marginp;
    float loss = 0.f;
    float rdl[8];
#pragma unroll
    for (int b = 0; b < 8; b++) rdl[b] = rnd[f * N + j0 + b * 16 + llo];

    __syncthreads();   // LDS buffers free -> reuse as key boards
#pragma unroll
    for (int a = 0; a < 2; a++) {
#pragma unroll
        for (int reg = 0; reg < 4; reg++) {
            const int rloc = wave * 32 + a * 16 + lhi * 4 + reg;
            const int i = i0 + rloc;
            const float rq = rnq[f * N + i];
            const float ds = diag_s[f * N + i];
            const float dl = diag_l[f * N + i];
            u64 bestS = 0ull, bestL = 0ull;
#pragma unroll
            for (int b = 0; b < 8; b++) {
                const int j = j0 + b * 16 + llo;
                const float sim = acc[a][b][reg] * rq * rdl[b];
                const float lb = lab[a][reg][b];
                // diagonal term == margin exactly (dl - lb == 0 bit-exact);
                // the aggregate margin*F*N is subtracted in reduce_kernel.
                const float term = fmaf(-(ds - sim), (dl - lb), margin);
                loss += fmaxf(term, 0.f);
                u64 ks = (((u64)fmap(sim)) << 32) | (u64)(~(unsigned)j);
                u64 kl = (((u64)(__float_as_uint(lb) | 0x80000000u)) << 32) | (u64)(~(unsigned)j);
                bestS = (ks > bestS) ? ks : bestS;
                bestL = (kl > bestL) ? kl : bestL;
            }
            kbS[rloc * 17 + llo] = bestS;
            kbL[rloc * 17 + llo] = bestL;
        }
    }
    __syncthreads();
    {   // plain coalesced partial-key stores (no atomics, no init needed)
        const int r = t & 127;
        const u64* kb = (t < 128) ? kbS : kbL;
        u64 best = 0ull;
#pragma unroll
        for (int k = 0; k < 16; k++) {
            u64 v = kb[r * 17 + k];
            best = (v > best) ? v : best;
        }
        u64* dst = (t < 128) ? psim : plab;
        dst[(size_t)blockIdx.x * (F * N) + f * N + i0 + r] = best;
    }

    for (int off = 32; off >= 1; off >>= 1) loss += __shfl_down(loss, off, 64);
    if ((t & 63) == 0) lred[t >> 6] = loss;
    __syncthreads();
    if (t == 0) atomicAdd(loss_acc, lred[0] + lred[1] + lred[2] + lred[3]);
}

// ---- reduce partial keys -> match count; last block writes outputs ----
__global__ __launch_bounds__(256) void reduce_kernel(
    const u64* __restrict__ psim, const u64* __restrict__ plab,
    int* __restrict__ cnt, const float* __restrict__ loss_acc,
    const float* __restrict__ marginp, float* __restrict__ out) {
    const int r = blockIdx.x * 256 + threadIdx.x;   // 0..F*N-1
    u64 bs = 0ull, bl = 0ull;
#pragma unroll
    for (int jb = 0; jb < 16; jb++) {
        u64 v = psim[(size_t)jb * (F * N) + r]; bs = (v > bs) ? v : bs;
        u64 w = plab[(size_t)jb * (F * N) + r]; bl = (w > bl) ? w : bl;
    }
    int c = ((unsigned)(bs & 0xFFFFFFFFull) == (unsigned)(bl & 0xFFFFFFFFull)) ? 1 : 0;
    for (int off = 32; off >= 1; off >>= 1) c += __shfl_down(c, off, 64);
    __shared__ int cred[4];
    __shared__ int isLast;
    if ((threadIdx.x & 63) == 0) cred[threadIdx.x >> 6] = c;
    __syncthreads();
    if (threadIdx.x == 0) {
        atomicAdd(cnt, cred[0] + cred[1] + cred[2] + cred[3]);
        __threadfence();
        int done = atomicAdd(cnt + 1, 1);
        isLast = (done == (int)gridDim.x - 1);
    }
    __syncthreads();
    if (isLast && threadIdx.x == 0) {
        __threadfence();
        out[0] = *loss_acc - (*marginp) * (float)(F * N);  // remove diagonal terms
        out[1] = (float)(*(volatile int*)cnt);
    }
}

extern "C" void kernel_launch(void* const* d_in, const int* in_sizes, int n_in,
                              void* d_out, int out_size, void* d_ws, size_t ws_size,
                              hipStream_t stream) {
    const float* om     = (const float*)d_in[0];
    const float* label  = (const float*)d_in[1];
    const float* margin = (const float*)d_in[2];
    (void)in_sizes; (void)n_in; (void)out_size; (void)ws_size;

    char* ws = (char*)d_ws;
    float* loss_acc = (float*)(ws + OFF_LOSS);
    int*   cnt      = (int*)(ws + OFF_CNT);
    u64*   psim     = (u64*)(ws + OFF_PSIM);
    u64*   plab     = (u64*)(ws + OFF_PLAB);
    float* rnq    = (float*)(ws + OFF_RNQ);
    float* rnd    = (float*)(ws + OFF_RND);
    float* diag_s = (float*)(ws + OFF_DIAGS);
    float* diag_l = (float*)(ws + OFF_DIAGL);
    _Float16* Qh  = (_Float16*)(ws + OFF_QH);
    _Float16* Dh  = (_Float16*)(ws + OFF_DH);

    pack_kernel<<<N / 2, 256, 0, stream>>>(om, label, Qh, Dh, rnq, rnd, diag_s, diag_l,
                                           (int*)ws);

    dim3 grid(N / 128, N / 128, F);
    main_kernel<<<grid, 256, 0, stream>>>(Qh, Dh, label, rnq, rnd, diag_s, diag_l,
                                          margin, psim, plab, loss_acc);

    reduce_kernel<<<F * N / 256, 256, 0, stream>>>(psim, plab, cnt, loss_acc, margin,
                                                   (float*)d_out);
}

// Round 10
// 219.570 us; speedup vs baseline: 1.4665x; 1.0100x over previous
//
#include <hip/hip_runtime.h>
#include <hip/hip_bf16.h>

static constexpr int N = 2048;
static constexpr int D = 128;
static constexpr int F = 8;

// ---------------- workspace layout (bytes) ----------------
static constexpr size_t OFF_LOSS = 0;        // float
static constexpr size_t OFF_CNT  = 4;        // int cnt + int done-counter (+pad)
static constexpr size_t OFF_PSIM = 1024;                      // u64 [16][F*N]
static constexpr size_t OFF_PLAB = 1024 + 2097152;            // u64 [16][F*N]
static constexpr size_t OFF_RNQ  = OFF_PLAB + 2097152;
static constexpr size_t OFF_RND  = OFF_RNQ + 65536;
static constexpr size_t OFF_DIAGS= OFF_RND + 65536;
static constexpr size_t OFF_DIAGL= OFF_DIAGS + 65536;
static constexpr size_t OFF_QH   = OFF_DIAGL + 65536;         // f16 [F][N][128]
static constexpr size_t OFF_DH   = OFF_QH + (size_t)F * N * D * 2;

typedef _Float16 half8 __attribute__((ext_vector_type(8)));
typedef __attribute__((ext_vector_type(4))) float f32x4;
typedef unsigned long long u64;

__device__ __forceinline__ unsigned fmap(float x) {
    unsigned u = __float_as_uint(x);
    return (u & 0x80000000u) ? ~u : (u | 0x80000000u);
}
__device__ __forceinline__ void gload_lds16(const void* g, void* l) {
    __builtin_amdgcn_global_load_lds(
        (const __attribute__((address_space(1))) void*)g,
        (__attribute__((address_space(3))) void*)l, 16, 0, 0);
}

// ---- pack + norms + diag: [2,N,D,F] -> Qh/Dh f16 [F][N][128]; fp32 diag ----
// Block 0 also zeroes the ws header (loss/cnt/done) -- replaces a memset dispatch.
__global__ __launch_bounds__(256) void pack_kernel(
    const float* __restrict__ om, const float* __restrict__ label,
    _Float16* __restrict__ Qh, _Float16* __restrict__ Dh,
    float* __restrict__ rnq, float* __restrict__ rnd,
    float* __restrict__ diag_s, float* __restrict__ diag_l,
    int* __restrict__ hdr) {
    __shared__ float buf[4][1152];    // [r2*2+side][k*9 + f] padded transpose
    const int i0 = blockIdx.x * 2;
    const int t = threadIdx.x;
    if (blockIdx.x == 0 && t < 4) hdr[t] = 0;
#pragma unroll
    for (int s = 0; s < 4; s++) {
        const int r2 = s >> 1, side = s & 1;
        float4 v = *(const float4*)(om + ((size_t)side * N + i0 + r2) * (D * F) + t * 4);
#pragma unroll
        for (int e = 0; e < 4; e++) {
            int g = t * 4 + e;
            buf[s][(g >> 3) * 9 + (g & 7)] = ((const float*)&v)[e];
        }
    }
    __syncthreads();
    const int r2 = t >> 7, f = (t >> 4) & 7, k8 = t & 15;
    float v0[8], v1[8];
#pragma unroll
    for (int j = 0; j < 8; j++) {
        v0[j] = buf[r2 * 2 + 0][(k8 * 8 + j) * 9 + f];
        v1[j] = buf[r2 * 2 + 1][(k8 * 8 + j) * 9 + f];
    }
    half8 H0, H1;
    float s0 = 0.f, s1 = 0.f, p = 0.f;
#pragma unroll
    for (int j = 0; j < 8; j++) {
        H0[j] = (_Float16)v0[j];
        H1[j] = (_Float16)v1[j];
        s0 += v0[j] * v0[j]; s1 += v1[j] * v1[j]; p += v0[j] * v1[j];
    }
    const int i = i0 + r2;
    const size_t base = ((size_t)f * N + i) * D + k8 * 8;
    *(half8*)&Qh[base] = H0;
    *(half8*)&Dh[base] = H1;
#pragma unroll
    for (int off = 1; off < 16; off <<= 1) {
        s0 += __shfl_xor(s0, off, 64);
        s1 += __shfl_xor(s1, off, 64);
        p  += __shfl_xor(p,  off, 64);
    }
    if (k8 == 0) {
        float rq = 1.0f / sqrtf(s0), rd = 1.0f / sqrtf(s1);
        rnq[f * N + i] = rq;
        rnd[f * N + i] = rd;
        diag_s[f * N + i] = p * rq * rd;
        diag_l[f * N + i] = label[((size_t)f * N + i) * N + i];
    }
}

// ---- fused f16 MFMA GEMM (128x128 tile, K=128 in ONE staging phase) ----
// R10: label prefetch issued AFTER the staging barrier.  The compiler's
// vmcnt(0) drain before s_barrier covers only the 64 KB tile staging; the
// 64 KB/block label traffic now overlaps the whole MFMA phase, with the
// epilogue's first use carrying the vmcnt wait.  Sim path bit-identical
// to R8/R9 (fixed-seed argmax, absmax==0).
__global__ __launch_bounds__(256, 2) void main_kernel(
    const _Float16* __restrict__ Qh, const _Float16* __restrict__ Dh,
    const float* __restrict__ label,
    const float* __restrict__ rnq, const float* __restrict__ rnd,
    const float* __restrict__ diag_s, const float* __restrict__ diag_l,
    const float* __restrict__ marginp,
    u64* __restrict__ psim, u64* __restrict__ plab,
    float* __restrict__ loss_acc) {
    __shared__ __align__(16) char smem[65536];
    _Float16* As = (_Float16*)smem;            // [128][128] swizzled
    _Float16* Bs = (_Float16*)(smem + 32768);
    u64* kbS = (u64*)smem;                     // [128][17] overlay (post-GEMM)
    u64* kbL = (u64*)(smem + 17408);
    __shared__ float lred[4];

    const int f = blockIdx.z;
    const int i0 = blockIdx.y * 128;
    const int j0 = blockIdx.x * 128;
    const int t = threadIdx.x;
    const int lane = t & 63, wave = t >> 6;
    const int lhi = lane >> 4, llo = lane & 15;

    f32x4 acc[2][8];
#pragma unroll
    for (int a = 0; a < 2; a++)
#pragma unroll
        for (int b = 0; b < 8; b++) acc[a][b] = (f32x4){0.f, 0.f, 0.f, 0.f};

    const char* Ag = (const char*)(Qh + ((size_t)f * N + i0) * D);
    const char* Bg = (const char*)(Dh + ((size_t)f * N + j0) * D);
    char* AsB = smem;
    char* BsB = smem + 32768;
    const int srow = t >> 4, schunk = t & 15;

#pragma unroll
    for (int p = 0; p < 8; p++) {
        const int row = srow + p * 16;
        const int gc = schunk ^ (row & 15);
        gload_lds16(Ag + (size_t)row * 256 + gc * 16, AsB + t * 16 + p * 4096);
        gload_lds16(Bg + (size_t)row * 256 + gc * 16, BsB + t * 16 + p * 4096);
    }
    __syncthreads();   // drains vmcnt: ONLY the 64 KB staging is outstanding here

    // label prefetch: issued now so it overlaps the entire MFMA phase
    float lab[2][4][8];
#pragma unroll
    for (int a = 0; a < 2; a++)
#pragma unroll
        for (int reg = 0; reg < 4; reg++) {
            const int rloc = wave * 32 + a * 16 + lhi * 4 + reg;
            const float* lrow = label + ((size_t)(f * N + i0 + rloc)) * N + j0 + llo;
#pragma unroll
            for (int b = 0; b < 8; b++) lab[a][reg][b] = lrow[b * 16];
        }

#pragma unroll
    for (int kk = 0; kk < 128; kk += 32) {
        const int kc = kk >> 3;
        half8 af[2], bfv[8];
#pragma unroll
        for (int a = 0; a < 2; a++) {
            const int R = wave * 32 + a * 16 + llo;
            af[a] = *(const half8*)&As[R * 128 + (((kc + lhi) ^ (R & 15)) * 8)];
        }
#pragma unroll
        for (int b = 0; b < 8; b++) {
            const int R = b * 16 + llo;
            bfv[b] = *(const half8*)&Bs[R * 128 + (((kc + lhi) ^ (R & 15)) * 8)];
        }
#pragma unroll
        for (int a = 0; a < 2; a++)
#pragma unroll
            for (int b = 0; b < 8; b++)
                acc[a][b] = __builtin_amdgcn_mfma_f32_16x16x32_f16(af[a], bfv[b], acc[a][b], 0, 0, 0);
    }

    // -------- epilogue: C/D layout col=lane&15, row=(lane>>4)*4+reg --------
    const float margin = *marginp;
    float loss = 0.f;
    float rdl[8];
#pragma unroll
    for (int b = 0; b < 8; b++) rdl[b] = rnd[f * N + j0 + b * 16 + llo];

    __syncthreads();   // LDS buffers free -> reuse as key boards
#pragma unroll
    for (int a = 0; a < 2; a++) {
#pragma unroll
        for (int reg = 0; reg < 4; reg++) {
            const int rloc = wave * 32 + a * 16 + lhi * 4 + reg;
            const int i = i0 + rloc;
            const float rq = rnq[f * N + i];
            const float ds = diag_s[f * N + i];
            const float dl = diag_l[f * N + i];
            u64 bestS = 0ull, bestL = 0ull;
#pragma unroll
            for (int b = 0; b < 8; b++) {
                const int j = j0 + b * 16 + llo;
                const float sim = acc[a][b][reg] * rq * rdl[b];
                const float lb = lab[a][reg][b];
                // diagonal term == margin exactly (dl - lb == 0 bit-exact);
                // the aggregate margin*F*N is subtracted in reduce_kernel.
                const float term = fmaf(-(ds - sim), (dl - lb), margin);
                loss += fmaxf(term, 0.f);
                u64 ks = (((u64)fmap(sim)) << 32) | (u64)(~(unsigned)j);
                u64 kl = (((u64)(__float_as_uint(lb) | 0x80000000u)) << 32) | (u64)(~(unsigned)j);
                bestS = (ks > bestS) ? ks : bestS;
                bestL = (kl > bestL) ? kl : bestL;
            }
            kbS[rloc * 17 + llo] = bestS;
            kbL[rloc * 17 + llo] = bestL;
        }
    }
    __syncthreads();
    {   // plain coalesced partial-key stores (no atomics, no init needed)
        const int r = t & 127;
        const u64* kb = (t < 128) ? kbS : kbL;
        u64 best = 0ull;
#pragma unroll
        for (int k = 0; k < 16; k++) {
            u64 v = kb[r * 17 + k];
            best = (v > best) ? v : best;
        }
        u64* dst = (t < 128) ? psim : plab;
        dst[(size_t)blockIdx.x * (F * N) + f * N + i0 + r] = best;
    }

    for (int off = 32; off >= 1; off >>= 1) loss += __shfl_down(loss, off, 64);
    if ((t & 63) == 0) lred[t >> 6] = loss;
    __syncthreads();
    if (t == 0) atomicAdd(loss_acc, lred[0] + lred[1] + lred[2] + lred[3]);
}

// ---- reduce partial keys -> match count; last block writes outputs ----
__global__ __launch_bounds__(256) void reduce_kernel(
    const u64* __restrict__ psim, const u64* __restrict__ plab,
    int* __restrict__ cnt, const float* __restrict__ loss_acc,
    const float* __restrict__ marginp, float* __restrict__ out) {
    const int r = blockIdx.x * 256 + threadIdx.x;   // 0..F*N-1
    u64 bs = 0ull, bl = 0ull;
#pragma unroll
    for (int jb = 0; jb < 16; jb++) {
        u64 v = psim[(size_t)jb * (F * N) + r]; bs = (v > bs) ? v : bs;
        u64 w = plab[(size_t)jb * (F * N) + r]; bl = (w > bl) ? w : bl;
    }
    int c = ((unsigned)(bs & 0xFFFFFFFFull) == (unsigned)(bl & 0xFFFFFFFFull)) ? 1 : 0;
    for (int off = 32; off >= 1; off >>= 1) c += __shfl_down(c, off, 64);
    __shared__ int cred[4];
    __shared__ int isLast;
    if ((threadIdx.x & 63) == 0) cred[threadIdx.x >> 6] = c;
    __syncthreads();
    if (threadIdx.x == 0) {
        atomicAdd(cnt, cred[0] + cred[1] + cred[2] + cred[3]);
        __threadfence();
        int done = atomicAdd(cnt + 1, 1);
        isLast = (done == (int)gridDim.x - 1);
    }
    __syncthreads();
    if (isLast && threadIdx.x == 0) {
        __threadfence();
        out[0] = *loss_acc - (*marginp) * (float)(F * N);  // remove diagonal terms
        out[1] = (float)(*(volatile int*)cnt);
    }
}

extern "C" void kernel_launch(void* const* d_in, const int* in_sizes, int n_in,
                              void* d_out, int out_size, void* d_ws, size_t ws_size,
                              hipStream_t stream) {
    const float* om     = (const float*)d_in[0];
    const float* label  = (const float*)d_in[1];
    const float* margin = (const float*)d_in[2];
    (void)in_sizes; (void)n_in; (void)out_size; (void)ws_size;

    char* ws = (char*)d_ws;
    float* loss_acc = (float*)(ws + OFF_LOSS);
    int*   cnt      = (int*)(ws + OFF_CNT);
    u64*   psim     = (u64*)(ws + OFF_PSIM);
    u64*   plab     = (u64*)(ws + OFF_PLAB);
    float* rnq    = (float*)(ws + OFF_RNQ);
    float* rnd    = (float*)(ws + OFF_RND);
    float* diag_s = (float*)(ws + OFF_DIAGS);
    float* diag_l = (float*)(ws + OFF_DIAGL);
    _Float16* Qh  = (_Float16*)(ws + OFF_QH);
    _Float16* Dh  = (_Float16*)(ws + OFF_DH);

    pack_kernel<<<N / 2, 256, 0, stream>>>(om, label, Qh, Dh, rnq, rnd, diag_s, diag_l,
                                           (int*)ws);

    dim3 grid(N / 128, N / 128, F);
    main_kernel<<<grid, 256, 0, stream>>>(Qh, Dh, label, rnq, rnd, diag_s, diag_l,
                                          margin, psim, plab, loss_acc);

    reduce_kernel<<<F * N / 256, 256, 0, stream>>>(psim, plab, cnt, loss_acc, margin,
                                                   (float*)d_out);
}